// Round 1
// baseline (288.873 us; speedup 1.0000x reference)
//
#include <hip/hip_runtime.h>
#include <hip/hip_bf16.h>

#define VOCAB 64
#define H 64
#define NB 128
#define SL 2048

// ---------------- Kernel A: per-token tables ----------------
// grid 64 (token), block 64 (dim i). Entire encoder depends only on token id.
__global__ __launch_bounds__(64) void k_tables(
    const float* __restrict__ embed, const float* __restrict__ w1, const float* __restrict__ b1,
    const float* __restrict__ w2, const float* __restrict__ b2,
    const float* __restrict__ ln_g, const float* __restrict__ ln_b,
    const float* __restrict__ Wk, const float* __restrict__ Wv, const float* __restrict__ Wq,
    float* __restrict__ Ktab, float* __restrict__ Vtab, float* __restrict__ qtab)
{
  const int t = blockIdx.x;
  const int i = threadIdx.x;
  __shared__ float h0s[H];
  __shared__ float ff1s[2 * H];
  __shared__ float hs[H];

  h0s[i] = embed[t * H + i];
  __syncthreads();

  float a0 = b1[i], a1 = b1[i + H];
#pragma unroll
  for (int j = 0; j < H; ++j) {
    a0 = fmaf(w1[i * H + j], h0s[j], a0);
    a1 = fmaf(w1[(i + H) * H + j], h0s[j], a1);
  }
  ff1s[i] = fmaxf(a0, 0.f);
  ff1s[i + H] = fmaxf(a1, 0.f);
  __syncthreads();

  float z = h0s[i] + b2[i];
#pragma unroll
  for (int o = 0; o < 2 * H; ++o) z = fmaf(w2[i * 2 * H + o], ff1s[o], z);

  // LayerNorm across the 64 lanes (block == 1 wave)
  float s = z;
#pragma unroll
  for (int m = 1; m < 64; m <<= 1) s += __shfl_xor(s, m);
  const float mu = s * (1.f / 64.f);
  const float d = z - mu;
  float s2 = d * d;
#pragma unroll
  for (int m = 1; m < 64; m <<= 1) s2 += __shfl_xor(s2, m);
  const float var = s2 * (1.f / 64.f);
  const float hv = d * rsqrtf(var + 1e-5f) * ln_g[i] + ln_b[i];
  hs[i] = hv;
  __syncthreads();

  float kk = 0.f, vv = 0.f, qq = 0.f;
#pragma unroll
  for (int j = 0; j < H; ++j) {
    const float hj = hs[j];
    kk = fmaf(Wk[i * H + j], hj, kk);
    vv = fmaf(Wv[i * H + j], hj, vv);
    qq = fmaf(Wq[i * H + j], hj, qq);
  }
  float n2 = kk * kk;
#pragma unroll
  for (int m = 1; m < 64; m <<= 1) n2 += __shfl_xor(n2, m);
  const float inv = 1.f / fmaxf(sqrtf(n2), 1e-12f);
  Ktab[t * H + i] = kk * inv;
  Vtab[t * H + i] = vv;
  qtab[t * H + i] = qq;
}

// ---------------- Kernel B: delta-rule scan ----------------
// Rows of M are independent: grid 256 = (batch, half-of-rows), block 256.
// thread owns row r = half*32 + (tid>>3), cols (tid&7)*8 .. +7  (8 elems in regs).
template <int CTRL>
__device__ __forceinline__ float dpp_add(float x) {
  int y = __builtin_amdgcn_update_dpp(0, __float_as_int(x), CTRL, 0xF, 0xF, false);
  return x + __int_as_float(y);
}

__global__ __launch_bounds__(256) void k_scan(
    const int* __restrict__ x, const float* __restrict__ Ktab, const float* __restrict__ Vtab,
    float* __restrict__ Mout)
{
  const int bb = blockIdx.x >> 1;
  const int half = blockIdx.x & 1;
  const int tid = threadIdx.x;

  __shared__ float Kt[VOCAB * H];
  __shared__ float Vt[VOCAB * H];
#pragma unroll
  for (int u = 0; u < 4; ++u) {
    ((float4*)Kt)[u * 256 + tid] = ((const float4*)Ktab)[u * 256 + tid];
    ((float4*)Vt)[u * 256 + tid] = ((const float4*)Vtab)[u * 256 + tid];
  }
  __syncthreads();

  const int r = half * 32 + (tid >> 3);
  const int c8 = (tid & 7) * 8;

  float M0 = 0.f, M1 = 0.f, M2 = 0.f, M3 = 0.f, M4 = 0.f, M5 = 0.f, M6 = 0.f, M7 = 0.f;
  const int* __restrict__ xrow = x + bb * SL;

  for (int t0 = 0; t0 < SL; t0 += 8) {
    int toks[8];
#pragma unroll
    for (int u = 0; u < 8; ++u) toks[u] = xrow[t0 + u];  // wave-uniform -> scalar loads
#pragma unroll
    for (int u = 0; u < 8; ++u) {
      const int base = toks[u] * H;
      const float4 k0 = *(const float4*)(&Kt[base + c8]);
      const float4 k1 = *(const float4*)(&Kt[base + c8 + 4]);
      const float v = Vt[base + r];
      // partial pred over this thread's 8 cols (2 chains)
      float pa = fmaf(k0.x, M0, fmaf(k0.y, M1, fmaf(k0.z, M2, k0.w * M3)));
      float pb = fmaf(k1.x, M4, fmaf(k1.y, M5, fmaf(k1.z, M6, k1.w * M7)));
      float p = pa + pb;
      // all-reduce over the 8 lanes of this row: xor1, xor2 (quad_perm), xor4 (row_half_mirror)
      p = dpp_add<0xB1>(p);
      p = dpp_add<0x4E>(p);
      p = dpp_add<0x141>(p);
      const float dl = v - p;
      M0 = fmaf(dl, k0.x, M0); M1 = fmaf(dl, k0.y, M1);
      M2 = fmaf(dl, k0.z, M2); M3 = fmaf(dl, k0.w, M3);
      M4 = fmaf(dl, k1.x, M4); M5 = fmaf(dl, k1.y, M5);
      M6 = fmaf(dl, k1.z, M6); M7 = fmaf(dl, k1.w, M7);
    }
  }
  float* mp = Mout + ((size_t)bb * H + r) * H + c8;
  float4 a; a.x = M0; a.y = M1; a.z = M2; a.w = M3;
  float4 b; b.x = M4; b.y = M5; b.z = M6; b.w = M7;
  *(float4*)mp = a;
  *(float4*)(mp + 4) = b;
}

// ---------------- Kernel C: attention + readout ----------------
// grid 128 (batch), block 64. Reads M (64x64) from ws.
__global__ __launch_bounds__(64) void k_final(
    const int* __restrict__ x, const float* __restrict__ Mws, const float* __restrict__ qtab,
    const float* __restrict__ Wout, const float* __restrict__ bout, float* __restrict__ out)
{
  const int b = blockIdx.x;
  const int i = threadIdx.x;
  __shared__ float Ml[H * 65];  // padded: col reads and row reads both conflict-free
  __shared__ float qs[H];
  __shared__ float attns[H];
  __shared__ float rcs[H];

  const float* Mg = Mws + (size_t)b * H * H;
#pragma unroll
  for (int j4 = 0; j4 < H; j4 += 4) {
    const float4 v = *(const float4*)(Mg + i * H + j4);
    Ml[i * 65 + j4 + 0] = v.x;
    Ml[i * 65 + j4 + 1] = v.y;
    Ml[i * 65 + j4 + 2] = v.z;
    Ml[i * 65 + j4 + 3] = v.w;
  }
  const int tok = x[b * SL + (SL - 1)];
  qs[i] = qtab[tok * H + i];
  __syncthreads();

  // scores_i = sum_j M[j,i] * q_j / 8
  float acc = 0.f;
#pragma unroll
  for (int j = 0; j < H; ++j) acc = fmaf(Ml[j * 65 + i], qs[j], acc);
  const float sc = acc * 0.125f;

  float mx = sc;
#pragma unroll
  for (int m = 1; m < 64; m <<= 1) mx = fmaxf(mx, __shfl_xor(mx, m));
  const float e = expf(sc - mx);
  float ssum = e;
#pragma unroll
  for (int m = 1; m < 64; m <<= 1) ssum += __shfl_xor(ssum, m);
  attns[i] = e / ssum;
  __syncthreads();

  // ctx_j = sum_i attn_i * M[j,i]   (thread j = i)
  float cx = 0.f;
#pragma unroll
  for (int jj = 0; jj < H; ++jj) cx = fmaf(attns[jj], Ml[i * 65 + jj], cx);
  rcs[i] = fmaxf(cx, 0.f);
  __syncthreads();

  // out_v = bout_v + sum_j relu(ctx_j) * Wout[v,j]
  float o = bout[i];
#pragma unroll
  for (int j = 0; j < H; ++j) o = fmaf(Wout[i * H + j], rcs[j], o);
  out[b * VOCAB + i] = o;
}

extern "C" void kernel_launch(void* const* d_in, const int* in_sizes, int n_in,
                              void* d_out, int out_size, void* d_ws, size_t ws_size,
                              hipStream_t stream) {
  const int*   x     = (const int*)d_in[0];
  const float* embed = (const float*)d_in[1];
  const float* w1    = (const float*)d_in[2];
  const float* b1    = (const float*)d_in[3];
  const float* w2    = (const float*)d_in[4];
  const float* b2    = (const float*)d_in[5];
  const float* ln_g  = (const float*)d_in[6];
  const float* ln_b  = (const float*)d_in[7];
  const float* Wk    = (const float*)d_in[8];
  const float* Wv    = (const float*)d_in[9];
  const float* Wq    = (const float*)d_in[10];
  const float* Wout  = (const float*)d_in[11];
  const float* bout  = (const float*)d_in[12];

  float* ws   = (float*)d_ws;
  float* Ktab = ws;                 // 4096
  float* Vtab = ws + 4096;          // 4096
  float* qtab = ws + 8192;          // 4096
  float* Mws  = ws + 12288;         // 128*4096

  k_tables<<<dim3(VOCAB), dim3(H), 0, stream>>>(embed, w1, b1, w2, b2, ln_g, ln_b,
                                                Wk, Wv, Wq, Ktab, Vtab, qtab);
  k_scan<<<dim3(2 * NB), dim3(256), 0, stream>>>(x, Ktab, Vtab, Mws);
  k_final<<<dim3(NB), dim3(H), 0, stream>>>(x, Mws, qtab, Wout, bout, (float*)d_out);
}